// Round 6
// baseline (442.014 us; speedup 1.0000x reference)
//
#include <hip/hip_runtime.h>
#include <hip/hip_fp16.h>
#include <stdint.h>

// AdaptiveGCN: B=8, L=128, D=768.  All-f16 MFMA pipeline.
// Algebra: denom==2.0 exactly; mask==all-False; (ax+out)@gw+2gb == ((a+I)@out)@gw+2gb;
// concat-linear splits into hi = x@w1[:D], hj = x@w1[D:].
// R6: edge kernel = zero-barrier register-resident K-loop (AITER-style):
//     w2 pre-packed in B-fragment order (w2p), aF formed in regs from hj loads
//     (L1-shared across 8 waves), 512-thread blocks, acc 96 f32/lane.

typedef __attribute__((ext_vector_type(8))) _Float16 half8;
typedef __attribute__((ext_vector_type(2))) _Float16 half2v;
typedef __attribute__((ext_vector_type(2))) __fp16 fp16x2;   // cvt_pkrtz ret type
typedef __attribute__((ext_vector_type(4))) float floatx4;

__device__ __forceinline__ unsigned short f2h(float f) {
    union { fp16x2 p; unsigned short s[2]; } v;
    v.p = __builtin_amdgcn_cvt_pkrtz(f, f);
    return v.s[0];
}
__device__ __forceinline__ half2v f2h2v(float a, float b) {
    union { fp16x2 p; half2v h; } v;
    v.p = __builtin_amdgcn_cvt_pkrtz(a, b);
    return v.h;
}
__device__ __forceinline__ floatx4 mfma16(half8 a, half8 b, floatx4 c) {
    return __builtin_amdgcn_mfma_f32_16x16x32_f16(a, b, c, 0, 0, 0);
}
__device__ __forceinline__ void gload16(const void* g, void* lds) {
    __builtin_amdgcn_global_load_lds(
        (const __attribute__((address_space(1))) void*)g,
        (__attribute__((address_space(3))) void*)lds, 16, 0, 0);
}

// ------- prep: weight transposes fp32->f16 [n][k]; w2 frag-pack; x; x^T -----
struct TJob { const float* src; unsigned short* dst; int R, C; };
struct TJobs { TJob j[5]; };

__global__ void prep_kernel(TJobs jobs, const float* __restrict__ x,
                            const float* __restrict__ w2,
                            unsigned short* __restrict__ w2p,
                            unsigned short* __restrict__ xh,
                            unsigned short* __restrict__ xhT,
                            float* __restrict__ maskout) {
    const int t = threadIdx.y * 32 + threadIdx.x;
    if (blockIdx.z == 5) {  // w2 (768x384 fp32 [k][n]) -> B-fragment packing
        const int s = blockIdx.x, ntg = blockIdx.y;  // both 0..23
        const int lane = t >> 2, e0 = (t & 3) * 2;
        const int n = ntg * 16 + (lane & 15);
        const int kbase = s * 32 + (lane >> 4) * 8;
        unsigned short* dst = w2p + (s * 24 + ntg) * 512 + lane * 8 + e0;
        dst[0] = f2h(w2[(kbase + e0) * 384 + n]);
        dst[1] = f2h(w2[(kbase + e0 + 1) * 384 + n]);
        return;
    }
    if (blockIdx.z == 6) {  // x fp32 -> f16 row-major, plus zero the mask outputs
        int gid = (blockIdx.y * 24 + blockIdx.x) * 256 + t;
        for (int i = gid; i < 786432; i += 24 * 24 * 256) xh[i] = f2h(x[i]);
        if (gid < 1024) maskout[gid] = 0.f;
        return;
    }
    TJob jb;
    if (blockIdx.z < 5) {
        jb = jobs.j[blockIdx.z];
    } else {  // z = 7..14: per-batch transpose x[b] (128x768) -> xhT[b] (768x128)
        int bz = blockIdx.z - 7;
        jb.src = x + bz * 98304; jb.dst = xhT + bz * 98304; jb.R = 128; jb.C = 768;
    }
    const int c0 = blockIdx.x * 32, r0 = blockIdx.y * 32;
    if (c0 >= jb.C || r0 >= jb.R) return;
    __shared__ float tile[32][33];
    const int tx = threadIdx.x, ty = threadIdx.y;  // 32 x 8
    #pragma unroll
    for (int yy = ty; yy < 32; yy += 8)
        tile[yy][tx] = jb.src[(r0 + yy) * jb.C + (c0 + tx)];
    __syncthreads();
    #pragma unroll
    for (int yy = ty; yy < 32; yy += 8)
        jb.dst[(c0 + yy) * jb.R + (r0 + tx)] = f2h(tile[tx][yy]);
}

// --------- 128x128-tile f16 GEMM: hi|hj = x @ [w1_top|w1_bot]^T -------------
// C[m][n] = sum_k A[m][k]*Bm[n][k].  n<768 -> hi fp32; n>=768 -> hjh f16.
__global__ __launch_bounds__(256) void gemm128_kernel(
    const unsigned short* __restrict__ A, const unsigned short* __restrict__ Bm,
    float* __restrict__ hi, unsigned short* __restrict__ hjh) {
    __shared__ __align__(16) unsigned short sA[128 * 32];
    __shared__ __align__(16) unsigned short sB[128 * 32];
    const int n0 = blockIdx.x * 128, m0 = blockIdx.y * 128;
    const int t = threadIdx.x, wave = t >> 6, lane = t & 63;
    const int wm = wave >> 1, wn = wave & 1, col = lane & 15, q = lane >> 4;

    floatx4 acc[4][4];
    #pragma unroll
    for (int mt = 0; mt < 4; ++mt)
        #pragma unroll
        for (int nt = 0; nt < 4; ++nt) acc[mt][nt] = (floatx4){0.f, 0.f, 0.f, 0.f};

    for (int k0 = 0; k0 < 768; k0 += 32) {
        #pragma unroll
        for (int c = 0; c < 2; ++c) {
            int cid = (wave * 2 + c) * 64 + lane;  // 0..511 chunks of 16B
            int rw = cid >> 2;
            int half = (cid & 3) ^ ((rw >> 1) & 3);  // XOR-swizzled placement
            gload16(A + (m0 + rw) * 768 + k0 + half * 8, (char*)sA + (wave * 2 + c) * 1024);
            gload16(Bm + (n0 + rw) * 768 + k0 + half * 8, (char*)sB + (wave * 2 + c) * 1024);
        }
        __syncthreads();
        half8 aF[4], bF[4];
        #pragma unroll
        for (int mt = 0; mt < 4; ++mt) {
            int r = wm * 64 + mt * 16 + col;
            aF[mt] = *(const half8*)&sA[r * 32 + (q ^ ((r >> 1) & 3)) * 8];
        }
        #pragma unroll
        for (int nt = 0; nt < 4; ++nt) {
            int r = wn * 64 + nt * 16 + col;
            bF[nt] = *(const half8*)&sB[r * 32 + (q ^ ((r >> 1) & 3)) * 8];
        }
        #pragma unroll
        for (int mt = 0; mt < 4; ++mt)
            #pragma unroll
            for (int nt = 0; nt < 4; ++nt)
                acc[mt][nt] = mfma16(aF[mt], bF[nt], acc[mt][nt]);
        __syncthreads();
    }
    #pragma unroll
    for (int mt = 0; mt < 4; ++mt)
        #pragma unroll
        for (int nt = 0; nt < 4; ++nt) {
            int mg = m0 + wm * 64 + mt * 16 + q * 4;
            int ng = n0 + wn * 64 + nt * 16 + col;
            if (ng < 768) {
                #pragma unroll
                for (int r = 0; r < 4; ++r) hi[(mg + r) * 768 + ng] = acc[mt][nt][r];
            } else {
                #pragma unroll
                for (int r = 0; r < 4; ++r) hjh[(mg + r) * 768 + (ng - 768)] = f2h(acc[mt][nt][r]);
            }
        }
}

// ------------- edge kernel: one block per (b,i); fully fused row -------------
// U = relu( relu(hi_i + hj + b1) @ w2 + b2 ); ew = sigmoid(U@w3 + b3);
// a_row = softmax(adj_row * ew + e_i)  -> ah (f16)
// 512 threads, 8 waves x 48 cols; zero barriers in K-loop; all operands in regs.
__global__ __launch_bounds__(512, 2) void edge_kernel(
    const float* __restrict__ hi, const unsigned short* __restrict__ hjh,
    const float* __restrict__ b1, const unsigned short* __restrict__ w2p,
    const float* __restrict__ b2, const float* __restrict__ w3,
    const float* __restrict__ b3, const float* __restrict__ adj,
    unsigned short* __restrict__ ah) {
    __shared__ __align__(16) half2v sHib[384];  // hi_i + b1, packed f16
    __shared__ float sEw[128];
    __shared__ float sRed[4];

    const int t = threadIdx.x;
    const int row_i = blockIdx.x;  // b*128 + i
    const int b = row_i >> 7, i = row_i & 127;

    if (t < 384) {
        float f0 = hi[row_i * 768 + 2 * t] + b1[2 * t];
        float f1 = hi[row_i * 768 + 2 * t + 1] + b1[2 * t + 1];
        sHib[t] = f2h2v(f0, f1);
    }
    if (t < 128) sEw[t] = 0.f;
    __syncthreads();

    const int wave = t >> 6, lane = t & 63;
    const int col = lane & 15, q = lane >> 4;
    const half2v z2 = {(_Float16)0.f, (_Float16)0.f};

    floatx4 acc[8][3];
    #pragma unroll
    for (int mt = 0; mt < 8; ++mt)
        #pragma unroll
        for (int nt = 0; nt < 3; ++nt) acc[mt][nt] = (floatx4){0.f, 0.f, 0.f, 0.f};

    // per-lane base pointers (A row = mt*16+col, k = step*32 + q*8)
    const unsigned short* hjb = hjh + (b * 128 + col) * 768 + q * 8;  // + mt*12288 + step*32
    const unsigned short* wp  = w2p + wave * 3 * 512 + lane * 8;      // + step*12288 + nt*512

    uint4 hjn[8], bfn[3];
    #pragma unroll
    for (int mt = 0; mt < 8; ++mt) hjn[mt] = *(const uint4*)(hjb + mt * 12288);
    #pragma unroll
    for (int nt = 0; nt < 3; ++nt) bfn[nt] = *(const uint4*)(wp + nt * 512);

    for (int step = 0; step < 24; ++step) {
        uint4 ch[8], cb[3];
        #pragma unroll
        for (int mt = 0; mt < 8; ++mt) ch[mt] = hjn[mt];
        #pragma unroll
        for (int nt = 0; nt < 3; ++nt) cb[nt] = bfn[nt];
        if (step < 23) {  // prefetch next step
            const unsigned short* hp = hjb + (step + 1) * 32;
            const unsigned short* wq = wp + (step + 1) * 12288;
            #pragma unroll
            for (int mt = 0; mt < 8; ++mt) hjn[mt] = *(const uint4*)(hp + mt * 12288);
            #pragma unroll
            for (int nt = 0; nt < 3; ++nt) bfn[nt] = *(const uint4*)(wq + nt * 512);
        }
        // hib chunk for this (step, q): 8 halves, broadcast across 16 cols
        union { uint4 u; half2v h[4]; } hb;
        hb.u = *(const uint4*)&sHib[step * 16 + q * 4];
        // form aF in regs: H[j][k] = relu(hib[k] + hj[j][k])
        half8 aF[8];
        #pragma unroll
        for (int mt = 0; mt < 8; ++mt) {
            union { uint4 u; half2v h[4]; half8 v; } hx;
            hx.u = ch[mt];
            #pragma unroll
            for (int e = 0; e < 4; ++e)
                hx.h[e] = __builtin_elementwise_max(hx.h[e] + hb.h[e], z2);
            aF[mt] = hx.v;
        }
        #pragma unroll
        for (int nt = 0; nt < 3; ++nt) {
            union { uint4 u; half8 v; } bx; bx.u = cb[nt];
            #pragma unroll
            for (int mt = 0; mt < 8; ++mt)
                acc[mt][nt] = mfma16(aF[mt], bx.v, acc[mt][nt]);
        }
    }

    // epilogue: ew_partial[j] += sum_n relu(U+b2)*w3[n]  (wave's 48-col slice)
    #pragma unroll
    for (int mt = 0; mt < 8; ++mt) {
        float s0 = 0.f, s1 = 0.f, s2 = 0.f, s3 = 0.f;
        #pragma unroll
        for (int nt = 0; nt < 3; ++nt) {
            int n = (wave * 3 + nt) * 16 + col;
            float w3n = w3[n], b2n = b2[n];
            s0 += fmaxf(acc[mt][nt][0] + b2n, 0.f) * w3n;
            s1 += fmaxf(acc[mt][nt][1] + b2n, 0.f) * w3n;
            s2 += fmaxf(acc[mt][nt][2] + b2n, 0.f) * w3n;
            s3 += fmaxf(acc[mt][nt][3] + b2n, 0.f) * w3n;
        }
        #pragma unroll
        for (int off = 1; off < 16; off <<= 1) {
            s0 += __shfl_xor(s0, off); s1 += __shfl_xor(s1, off);
            s2 += __shfl_xor(s2, off); s3 += __shfl_xor(s3, off);
        }
        if (col == 0) {
            int r = mt * 16 + q * 4;
            atomicAdd(&sEw[r + 0], s0); atomicAdd(&sEw[r + 1], s1);
            atomicAdd(&sEw[r + 2], s2); atomicAdd(&sEw[r + 3], s3);
        }
    }
    __syncthreads();
    // sigmoid -> adj*ew + I -> softmax over j (threads 0..127)
    float logit = -1e30f;
    if (t < 128) {
        float p = sEw[t] + b3[0];
        float ew = 1.f / (1.f + expf(-p));
        logit = adj[row_i * 128 + t] * ew + (t == i ? 1.f : 0.f);
    }
    float mx = logit;
    #pragma unroll
    for (int off = 1; off < 64; off <<= 1) mx = fmaxf(mx, __shfl_xor(mx, off));
    if (lane == 0 && wave < 2) sRed[wave] = mx;
    __syncthreads();
    mx = fmaxf(sRed[0], sRed[1]);
    float e = (t < 128) ? expf(logit - mx) : 0.f;
    float sm = e;
    #pragma unroll
    for (int off = 1; off < 64; off <<= 1) sm += __shfl_xor(sm, off);
    if (lane == 0 && wave < 2) sRed[2 + wave] = sm;
    __syncthreads();
    float tot = sRed[2] + sRed[3];
    if (t < 128) ah[row_i * 128 + t] = f2h(e / tot);
}

// ------ one GCN layer, fully block-local (no grid sync inside a layer) ------
// block = (batch b, 16 tokens t0..t0+15).  grid = 64 x 256.
__global__ __launch_bounds__(256) void gcn_layer_kernel(
    const unsigned short* __restrict__ ah, const unsigned short* __restrict__ srcT,
    const unsigned short* __restrict__ gwl, const float* __restrict__ gb,
    const float* __restrict__ lng, const float* __restrict__ lnb,
    unsigned short* __restrict__ dstT, float* __restrict__ outf) {
    __shared__ __align__(16) unsigned short sBuf[16 * 776];  // axh / yT (reused)
    __shared__ float sSum[16], sSq[16];

    const int b = blockIdx.x >> 3, t0 = (blockIdx.x & 7) * 16;
    const int t = threadIdx.x, wave = t >> 6, lane = t & 63;
    const int col = lane & 15, q = lane >> 4;
    if (t < 16) { sSum[t] = 0.f; sSq[t] = 0.f; }

    // ---- phase 1: ax = (a+I) @ src ----
    floatx4 acc[12];
    #pragma unroll
    for (int nt = 0; nt < 12; ++nt) acc[nt] = (floatx4){0.f, 0.f, 0.f, 0.f};
    {
        const unsigned short* arow = ah + (b * 128 + t0 + col) * 128;
        const int token = t0 + col;
        half8 aF1[4];
        #pragma unroll
        for (int kc = 0; kc < 4; ++kc) {
            aF1[kc] = *(const half8*)&arow[kc * 32 + q * 8];
            int kb = kc * 32 + q * 8;
            if (token >= kb && token < kb + 8)  // += identity
                aF1[kc][token - kb] = (_Float16)((float)aF1[kc][token - kb] + 1.0f);
        }
        #pragma unroll
        for (int kc = 0; kc < 4; ++kc)
            #pragma unroll
            for (int nt = 0; nt < 12; ++nt) {
                int n = wave * 192 + nt * 16 + col;
                half8 bF = *(const half8*)&srcT[(b * 768 + n) * 128 + kc * 32 + q * 8];
                acc[nt] = mfma16(aF1[kc], bF, acc[nt]);
            }
    }
    // ax -> LDS in A-layout (axh[m][k], stride 776)
    #pragma unroll
    for (int nt = 0; nt < 12; ++nt) {
        int n = wave * 192 + nt * 16 + col;
        #pragma unroll
        for (int r = 0; r < 4; ++r)
            sBuf[(q * 4 + r) * 776 + n] = f2h(acc[nt][r]);
    }
    __syncthreads();

    // ---- phase 2: Y = ax @ gw ----
    floatx4 acc2[12];
    #pragma unroll
    for (int nt = 0; nt < 12; ++nt) acc2[nt] = (floatx4){0.f, 0.f, 0.f, 0.f};
    for (int k0 = 0; k0 < 768; k0 += 32) {
        half8 aF = *(const half8*)&sBuf[col * 776 + k0 + q * 8];
        #pragma unroll
        for (int nt = 0; nt < 12; ++nt) {
            int n = wave * 192 + nt * 16 + col;
            half8 bF = *(const half8*)&gwl[n * 768 + k0 + q * 8];
            acc2[nt] = mfma16(aF, bF, acc2[nt]);
        }
    }

    // ---- epilogue: *0.5+gb, relu, LayerNorm ----
    float ps[4] = {0.f, 0.f, 0.f, 0.f}, pq2[4] = {0.f, 0.f, 0.f, 0.f};
    #pragma unroll
    for (int nt = 0; nt < 12; ++nt) {
        int n = wave * 192 + nt * 16 + col;
        float g = gb[n];
        #pragma unroll
        for (int r = 0; r < 4; ++r) {
            float v = fmaxf(acc2[nt][r] * 0.5f + g, 0.f);  // /denom, denom==2
            acc2[nt][r] = v;
            ps[r] += v; pq2[r] += v * v;
        }
    }
    #pragma unroll
    for (int off = 1; off < 16; off <<= 1) {
        #pragma unroll
        for (int r = 0; r < 4; ++r) {
            ps[r] += __shfl_xor(ps[r], off);
            pq2[r] += __shfl_xor(pq2[r], off);
        }
    }
    if (col == 0) {
        #pragma unroll
        for (int r = 0; r < 4; ++r) {
            atomicAdd(&sSum[q * 4 + r], ps[r]);
            atomicAdd(&sSq[q * 4 + r], pq2[r]);
        }
    }
    __syncthreads();  // also guarantees all waves are done reading sBuf (axh)
    float mean[4], rstd[4];
    #pragma unroll
    for (int r = 0; r < 4; ++r) {
        float mu = sSum[q * 4 + r] * (1.f / 768.f);
        float va = sSq[q * 4 + r] * (1.f / 768.f) - mu * mu;  // biased var (jnp.var)
        mean[r] = mu; rstd[r] = rsqrtf(va + 1e-5f);
    }
    if (outf) {  // last layer: fp32 row-major
        #pragma unroll
        for (int nt = 0; nt < 12; ++nt) {
            int n = wave * 192 + nt * 16 + col;
            float ga = lng[n], be = lnb[n];
            #pragma unroll
            for (int r = 0; r < 4; ++r) {
                float o = (acc2[nt][r] - mean[r]) * rstd[r] * ga + be;
                outf[(b * 128 + t0 + q * 4 + r) * 768 + n] = o;
            }
        }
    } else {     // intermediate: assemble Y^T in LDS, then 32B rows to dstT
        #pragma unroll
        for (int nt = 0; nt < 12; ++nt) {
            int n = wave * 192 + nt * 16 + col;
            float ga = lng[n], be = lnb[n];
            #pragma unroll
            for (int r = 0; r < 4; ++r) {
                float o = (acc2[nt][r] - mean[r]) * rstd[r] * ga + be;
                sBuf[n * 16 + (q * 4 + r)] = f2h(o);  // yT[dim][tok]
            }
        }
        __syncthreads();
        #pragma unroll
        for (int rr = 0; rr < 3; ++rr) {
            int row = t * 3 + rr;  // dim 0..767
            uint4 v0 = *(const uint4*)&sBuf[row * 16];
            uint4 v1 = *(const uint4*)&sBuf[row * 16 + 8];
            uint4* gp = (uint4*)&dstT[(b * 768 + row) * 128 + t0];
            gp[0] = v0; gp[1] = v1;
        }
    }
}

// ------------------------------- launch -------------------------------------
extern "C" void kernel_launch(void* const* d_in, const int* in_sizes, int n_in,
                              void* d_out, int out_size, void* d_ws, size_t ws_size,
                              hipStream_t stream) {
    const float* adj = (const float*)d_in[0];
    const float* x   = (const float*)d_in[1];
    const float* w1  = (const float*)d_in[2];
    const float* b1  = (const float*)d_in[3];
    const float* w2  = (const float*)d_in[4];
    const float* b2  = (const float*)d_in[5];
    const float* w3  = (const float*)d_in[6];
    const float* b3  = (const float*)d_in[7];
    const float* gw  = (const float*)d_in[8];
    const float* gb  = (const float*)d_in[9];
    const float* lng = (const float*)d_in[10];
    const float* lnb = (const float*)d_in[11];
    float* outp = (float*)d_out;  // 786432 out + 1024 mask

    char* ws = (char*)d_ws;
    unsigned short* w1t = (unsigned short*)(ws + 0);         // 1536x768 f16 [n][k]
    unsigned short* w2p = (unsigned short*)(ws + 2359296);   // 24x24x512 f16 frag-packed
    unsigned short* gwt = (unsigned short*)(ws + 2949120);   // 3x768x768 f16 [n][k]
    unsigned short* xh  = (unsigned short*)(ws + 6488064);   // 1024x768 f16
    float*          hi  = (float*)        (ws + 8060928);    // 1024x768 fp32
    unsigned short* hjh = (unsigned short*)(ws + 11206656);  // 1024x768 f16
    unsigned short* ah  = (unsigned short*)(ws + 12779520);  // 8x128x128 f16
    unsigned short* xhT = (unsigned short*)(ws + 13041664);  // 8x768x128 f16 (x^T)
    // ping-pong out^T buffers alias dead regions:
    unsigned short* obT0 = (unsigned short*)(ws + 0);        // over w1t (dead after gemm128)
    unsigned short* obT1 = (unsigned short*)(ws + 8060928);  // over hi  (dead after edge)

    TJobs jobs;
    jobs.j[0] = { w1,              w1t,              768, 768 };
    jobs.j[1] = { w1 + 768 * 768,  w1t + 768 * 768,  768, 768 };
    jobs.j[2] = { gw,              gwt,              768, 768 };
    jobs.j[3] = { gw + 589824,     gwt + 589824,     768, 768 };
    jobs.j[4] = { gw + 2 * 589824, gwt + 2 * 589824, 768, 768 };

    prep_kernel<<<dim3(24, 24, 15), dim3(32, 8), 0, stream>>>(jobs, x, w2, w2p,
                                                              xh, xhT, outp + 786432);
    gemm128_kernel<<<dim3(12, 8), 256, 0, stream>>>(xh, w1t, hi, hjh);
    edge_kernel<<<1024, 512, 0, stream>>>(hi, hjh, b1, w2p, b2, w3, b3, adj, ah);

    gcn_layer_kernel<<<64, 256, 0, stream>>>(ah, xhT,  gwt,          gb,
                                             lng,       lnb,          obT0, nullptr);
    gcn_layer_kernel<<<64, 256, 0, stream>>>(ah, obT0, gwt + 589824, gb + 768,
                                             lng + 768, lnb + 768,    obT1, nullptr);
    gcn_layer_kernel<<<64, 256, 0, stream>>>(ah, obT1, gwt + 1179648, gb + 1536,
                                             lng + 1536, lnb + 1536,  nullptr, outp);
}

// Round 7
// 263.110 us; speedup vs baseline: 1.6800x; 1.6800x over previous
//
#include <hip/hip_runtime.h>
#include <hip/hip_fp16.h>
#include <stdint.h>

// AdaptiveGCN: B=8, L=128, D=768.  All-f16 MFMA pipeline.
// Algebra: denom==2.0 exactly; mask==all-False; (ax+out)@gw+2gb == ((a+I)@out)@gw+2gb;
// concat-linear splits into hi = x@w1[:D], hj = x@w1[D:].
// R7: edge = R5 LDS-staged structure + frag-packed W (sequential DMA, 0 conflicts)
//     + 2 rows/block (W staged once per 2 H-tiles, 96 MFMA/barrier).
//     GCN = 256-block kernelA (Y + atomic LN stats) + 1024-block kernelB
//     (normalize + frag-pack for next layer); all B-operands frag-packed.

typedef __attribute__((ext_vector_type(8))) _Float16 half8;
typedef __attribute__((ext_vector_type(2))) _Float16 half2v;
typedef __attribute__((ext_vector_type(2))) __fp16 fp16x2;   // cvt_pkrtz ret type
typedef __attribute__((ext_vector_type(4))) float floatx4;

__device__ __forceinline__ unsigned short f2h(float f) {
    union { fp16x2 p; unsigned short s[2]; } v;
    v.p = __builtin_amdgcn_cvt_pkrtz(f, f);
    return v.s[0];
}
__device__ __forceinline__ half2v f2h2v(float a, float b) {
    union { fp16x2 p; half2v h; } v;
    v.p = __builtin_amdgcn_cvt_pkrtz(a, b);
    return v.h;
}
__device__ __forceinline__ float h2f(unsigned short u) {
    union { unsigned short u; _Float16 h; } c; c.u = u;
    return (float)c.h;
}
__device__ __forceinline__ floatx4 mfma16(half8 a, half8 b, floatx4 c) {
    return __builtin_amdgcn_mfma_f32_16x16x32_f16(a, b, c, 0, 0, 0);
}
__device__ __forceinline__ void gload16(const void* g, void* lds) {
    __builtin_amdgcn_global_load_lds(
        (const __attribute__((address_space(1))) void*)g,
        (__attribute__((address_space(3))) void*)lds, 16, 0, 0);
}

// B-fragment pack layout: tile(s = k-chunk of 32, ntile = n-group of 16) is 512
// shorts; element (n_local, k_local) at lane=(k_local>>3)*16+n_local, e=k_local&7.

// ---------------- prep: all weight conversions / packings -------------------
__global__ void prep_kernel(const float* __restrict__ x, const float* __restrict__ w1,
                            const float* __restrict__ w2, const float* __restrict__ gw,
                            unsigned short* __restrict__ w1t,
                            unsigned short* __restrict__ w2p,
                            unsigned short* __restrict__ gwp,
                            unsigned short* __restrict__ xh,
                            unsigned short* __restrict__ xpk,
                            float* __restrict__ maskout) {
    const int z = blockIdx.z;
    const int tx = threadIdx.x, ty = threadIdx.y;  // 32 x 8
    const int t = ty * 32 + tx;

    if (z == 5) {  // w2 (768x384 fp32 [k][n]) -> w2p frag tiles (s*24+ntg)*512
        const int s = blockIdx.x, ntg = blockIdx.y;  // both 0..23
        const int lane = t >> 2, e0 = (t & 3) * 2;
        const int n = ntg * 16 + (lane & 15);
        const int kbase = s * 32 + (lane >> 4) * 8;
        unsigned short* dst = w2p + (s * 24 + ntg) * 512 + lane * 8 + e0;
        dst[0] = f2h(w2[(kbase + e0) * 384 + n]);
        dst[1] = f2h(w2[(kbase + e0 + 1) * 384 + n]);
        return;
    }
    if (z == 6) {  // x fp32 -> f16 row-major, plus zero the mask outputs
        int gid = (blockIdx.y * 24 + blockIdx.x) * 256 + t;
        for (int i = gid; i < 786432; i += 24 * 24 * 256) xh[i] = f2h(x[i]);
        if (gid < 1024) maskout[gid] = 0.f;
        return;
    }
    if (z < 2) {  // w1 halves: transpose 768x768 fp32 -> f16 [n][k]
        const float* src = w1 + z * 589824;
        unsigned short* dst = w1t + z * 589824;
        const int c0 = blockIdx.x * 32, r0 = blockIdx.y * 32;
        __shared__ float tile[32][33];
        #pragma unroll
        for (int yy = ty; yy < 32; yy += 8)
            tile[yy][tx] = src[(r0 + yy) * 768 + (c0 + tx)];
        __syncthreads();
        #pragma unroll
        for (int yy = ty; yy < 32; yy += 8)
            dst[(c0 + yy) * 768 + (r0 + tx)] = f2h(tile[tx][yy]);
        return;
    }
    // frag-pack paths: z=2..4 -> gw layer (768x768 [k][n]); z=7..14 -> x batch
    const float* src; unsigned short* dstb; long tprefix; int rows;
    if (z <= 4) {
        int li = z - 2;
        src = gw + li * 589824; dstb = gwp + (long)li * 589824;
        tprefix = 0; rows = 768;
    } else {
        int bz = z - 7;
        src = x + bz * 98304; dstb = xpk;
        tprefix = (long)bz * 4; rows = 128;  // tile idx = (bz*4 + s)*48 + ntile
    }
    const int c0 = blockIdx.x * 32, r0 = blockIdx.y * 32;
    if (r0 >= rows) return;
    __shared__ float tile[32][33];
    #pragma unroll
    for (int yy = ty; yy < 32; yy += 8)
        tile[yy][tx] = src[(r0 + yy) * 768 + (c0 + tx)];
    __syncthreads();
    if (t < 128) {  // 128 chunks of 8 shorts (16B)
        const int n_off = t & 31, kg = t >> 5;   // kg 0..3
        const int s = r0 >> 5;
        long tileIdx = (tprefix + s) * 48 + (c0 >> 4) + (n_off >> 4);
        unsigned short* dst = dstb + tileIdx * 512 + (kg * 16 + (n_off & 15)) * 8;
        union { uint4 u; unsigned short s[8]; } pk;
        #pragma unroll
        for (int e = 0; e < 8; ++e) pk.s[e] = f2h(tile[kg * 8 + e][n_off]);
        *(uint4*)dst = pk.u;
    }
}

// --------- 128x128-tile f16 GEMM: hi|hj = x @ [w1_top|w1_bot]^T -------------
__global__ __launch_bounds__(256) void gemm128_kernel(
    const unsigned short* __restrict__ A, const unsigned short* __restrict__ Bm,
    float* __restrict__ hi, unsigned short* __restrict__ hjh) {
    __shared__ __align__(16) unsigned short sA[128 * 32];
    __shared__ __align__(16) unsigned short sB[128 * 32];
    const int n0 = blockIdx.x * 128, m0 = blockIdx.y * 128;
    const int t = threadIdx.x, wave = t >> 6, lane = t & 63;
    const int wm = wave >> 1, wn = wave & 1, col = lane & 15, q = lane >> 4;

    floatx4 acc[4][4];
    #pragma unroll
    for (int mt = 0; mt < 4; ++mt)
        #pragma unroll
        for (int nt = 0; nt < 4; ++nt) acc[mt][nt] = (floatx4){0.f, 0.f, 0.f, 0.f};

    for (int k0 = 0; k0 < 768; k0 += 32) {
        #pragma unroll
        for (int c = 0; c < 2; ++c) {
            int cid = (wave * 2 + c) * 64 + lane;
            int rw = cid >> 2;
            int half = (cid & 3) ^ ((rw >> 1) & 3);
            gload16(A + (m0 + rw) * 768 + k0 + half * 8, (char*)sA + (wave * 2 + c) * 1024);
            gload16(Bm + (n0 + rw) * 768 + k0 + half * 8, (char*)sB + (wave * 2 + c) * 1024);
        }
        __syncthreads();
        half8 aF[4], bF[4];
        #pragma unroll
        for (int mt = 0; mt < 4; ++mt) {
            int r = wm * 64 + mt * 16 + col;
            aF[mt] = *(const half8*)&sA[r * 32 + (q ^ ((r >> 1) & 3)) * 8];
        }
        #pragma unroll
        for (int nt = 0; nt < 4; ++nt) {
            int r = wn * 64 + nt * 16 + col;
            bF[nt] = *(const half8*)&sB[r * 32 + (q ^ ((r >> 1) & 3)) * 8];
        }
        #pragma unroll
        for (int mt = 0; mt < 4; ++mt)
            #pragma unroll
            for (int nt = 0; nt < 4; ++nt)
                acc[mt][nt] = mfma16(aF[mt], bF[nt], acc[mt][nt]);
        __syncthreads();
    }
    #pragma unroll
    for (int mt = 0; mt < 4; ++mt)
        #pragma unroll
        for (int nt = 0; nt < 4; ++nt) {
            int mg = m0 + wm * 64 + mt * 16 + q * 4;
            int ng = n0 + wn * 64 + nt * 16 + col;
            if (ng < 768) {
                #pragma unroll
                for (int r = 0; r < 4; ++r) hi[(mg + r) * 768 + ng] = acc[mt][nt][r];
            } else {
                #pragma unroll
                for (int r = 0; r < 4; ++r) hjh[(mg + r) * 768 + (ng - 768)] = f2h(acc[mt][nt][r]);
            }
        }
}

// ------------- edge kernel: one block per (b, 2 rows i); fused ---------------
// 512 threads = 8 waves; waves 0-3 row A, 4-7 row B; each wave 96 N-cols.
__global__ __launch_bounds__(512, 2) void edge_kernel(
    const float* __restrict__ hi, const unsigned short* __restrict__ hjh,
    const float* __restrict__ b1, const unsigned short* __restrict__ w2p,
    const float* __restrict__ b2, const float* __restrict__ w3,
    const float* __restrict__ b3, const float* __restrict__ adj,
    unsigned short* __restrict__ ah, float* __restrict__ stats) {
    __shared__ __align__(16) unsigned short sW[24 * 512];   // one step's W, frag order
    __shared__ __align__(16) unsigned short sH[2][128 * 40];
    __shared__ __align__(16) half2v sHib[2][384];
    __shared__ float sEw[2][128];
    __shared__ float sRed[8];

    const int t = threadIdx.x;
    const int rowA = blockIdx.x * 2;
    const int b = rowA >> 7, iA = rowA & 127;

    if (blockIdx.x < 4) stats[blockIdx.x * 512 + t] = 0.f;  // zero LN stats (2048 f32)

    for (int kk = t; kk < 768; kk += 512) {
        int rr = kk >= 384 ? 1 : 0; int k = kk - rr * 384;
        float f0 = hi[(rowA + rr) * 768 + 2 * k] + b1[2 * k];
        float f1 = hi[(rowA + rr) * 768 + 2 * k + 1] + b1[2 * k + 1];
        sHib[rr][k] = f2h2v(f0, f1);
    }
    if (t < 256) sEw[t >> 7][t & 127] = 0.f;
    __syncthreads();

    const int wave = t >> 6, lane = t & 63;
    const int col = lane & 15, q = lane >> 4;
    const int rsel = wave >> 2, wq = wave & 3;
    // H-formation mapping: threads 0-255 -> sH[0], 256-511 -> sH[1]
    const int hgrp = t >> 8;
    const int tt = t & 255, hj_j = tt >> 1, hk = (tt & 1) * 16;
    const unsigned short* hjrow = hjh + (b * 128 + hj_j) * 768;
    const half2v* hibp = sHib[hgrp];
    const half2v z2 = {(_Float16)0.f, (_Float16)0.f};

    floatx4 acc[8][6];
    #pragma unroll
    for (int mt = 0; mt < 8; ++mt)
        #pragma unroll
        for (int nt = 0; nt < 6; ++nt) acc[mt][nt] = (floatx4){0.f, 0.f, 0.f, 0.f};

    uint4 nh0 = *(const uint4*)(hjrow + hk);
    uint4 nh1 = *(const uint4*)(hjrow + hk + 8);

    for (int step = 0; step < 24; ++step) {
        // stage W (24KB, frag order, perfectly sequential)
        #pragma unroll
        for (int c = 0; c < 3; ++c)
            gload16(w2p + step * 12288 + (wave * 3 + c) * 512 + lane * 8,
                    &sW[(wave * 3 + c) * 512]);
        // form my H tile
        union U4 { uint4 u; half2v h[4]; } a0, a1;
        a0.u = nh0; a1.u = nh1;
        if (step < 23) {
            nh0 = *(const uint4*)(hjrow + (step + 1) * 32 + hk);
            nh1 = *(const uint4*)(hjrow + (step + 1) * 32 + hk + 8);
        }
        const half2v* hib = &hibp[step * 16 + (hk >> 1)];
        #pragma unroll
        for (int e = 0; e < 4; ++e) {
            a0.h[e] = __builtin_elementwise_max(a0.h[e] + hib[e], z2);
            a1.h[e] = __builtin_elementwise_max(a1.h[e] + hib[e + 4], z2);
        }
        *(uint4*)&sH[hgrp][hj_j * 40 + hk] = a0.u;
        *(uint4*)&sH[hgrp][hj_j * 40 + hk + 8] = a1.u;
        __syncthreads();

        half8 aF[8];
        #pragma unroll
        for (int mt = 0; mt < 8; ++mt)
            aF[mt] = *(const half8*)&sH[rsel][(mt * 16 + col) * 40 + q * 8];
        #pragma unroll
        for (int nt = 0; nt < 6; ++nt) {
            half8 bF = *(const half8*)&sW[(wq * 6 + nt) * 512 + lane * 8];
            #pragma unroll
            for (int mt = 0; mt < 8; ++mt)
                acc[mt][nt] = mfma16(aF[mt], bF, acc[mt][nt]);
        }
        __syncthreads();
    }

    // epilogue: ew_partial[j] += sum_n relu(U+b2)*w3[n]
    #pragma unroll
    for (int mt = 0; mt < 8; ++mt) {
        float s0 = 0.f, s1 = 0.f, s2 = 0.f, s3 = 0.f;
        #pragma unroll
        for (int nt = 0; nt < 6; ++nt) {
            int n = wq * 96 + nt * 16 + col;
            float w3n = w3[n], b2n = b2[n];
            s0 += fmaxf(acc[mt][nt][0] + b2n, 0.f) * w3n;
            s1 += fmaxf(acc[mt][nt][1] + b2n, 0.f) * w3n;
            s2 += fmaxf(acc[mt][nt][2] + b2n, 0.f) * w3n;
            s3 += fmaxf(acc[mt][nt][3] + b2n, 0.f) * w3n;
        }
        #pragma unroll
        for (int off = 1; off < 16; off <<= 1) {
            s0 += __shfl_xor(s0, off); s1 += __shfl_xor(s1, off);
            s2 += __shfl_xor(s2, off); s3 += __shfl_xor(s3, off);
        }
        if (col == 0) {
            int r = mt * 16 + q * 4;
            atomicAdd(&sEw[rsel][r + 0], s0); atomicAdd(&sEw[rsel][r + 1], s1);
            atomicAdd(&sEw[rsel][r + 2], s2); atomicAdd(&sEw[rsel][r + 3], s3);
        }
    }
    __syncthreads();
    // softmax: waves 0-1 -> row A, waves 2-3 -> row B
    float logit = -1e30f;
    int rr = (t >> 7) & 1, j = t & 127;
    if (t < 256) {
        float p = sEw[rr][j] + b3[0];
        float ew = 1.f / (1.f + expf(-p));
        logit = adj[(rowA + rr) * 128 + j] * ew + (j == iA + rr ? 1.f : 0.f);
    }
    float mx = logit;
    #pragma unroll
    for (int off = 1; off < 64; off <<= 1) mx = fmaxf(mx, __shfl_xor(mx, off));
    if (lane == 0 && wave < 4) sRed[wave] = mx;
    __syncthreads();
    float mrow = fmaxf(sRed[rr * 2], sRed[rr * 2 + 1]);
    float e = (t < 256) ? expf(logit - mrow) : 0.f;
    float sm = e;
    #pragma unroll
    for (int off = 1; off < 64; off <<= 1) sm += __shfl_xor(sm, off);
    if (lane == 0 && wave < 4) sRed[4 + wave] = sm;
    __syncthreads();
    float tot = sRed[4 + rr * 2] + sRed[5 + rr * 2];
    if (t < 256) ah[(rowA + rr) * 128 + j] = f2h(e / tot);
}

// ---- GCN kernelA: Y = ((a+I)@src)@gw, relu(.5Y+gb), atomic LN stats --------
// grid (4 n-quarters, 8 token-tiles, 8 batches) x 256 threads.
__global__ __launch_bounds__(256) void gcnA_kernel(
    const unsigned short* __restrict__ ah, const unsigned short* __restrict__ srcpk,
    const unsigned short* __restrict__ gwp_l, const float* __restrict__ gb_l,
    unsigned short* __restrict__ yb, float* __restrict__ gS, float* __restrict__ gQ) {
    __shared__ __align__(16) unsigned short sBuf[16 * 776];
    const int nq = blockIdx.x, t0 = blockIdx.y * 16, b = blockIdx.z;
    const int t = threadIdx.x, wave = t >> 6, lane = t & 63;
    const int col = lane & 15, q = lane >> 4;

    // phase 1: ax[16][768]; wave w computes cols [w*192, +192)
    {
        floatx4 acc1[12];
        #pragma unroll
        for (int nt = 0; nt < 12; ++nt) acc1[nt] = (floatx4){0.f, 0.f, 0.f, 0.f};
        const unsigned short* arow = ah + (b * 128 + t0 + col) * 128;
        const int token = t0 + col;
        #pragma unroll
        for (int kc = 0; kc < 4; ++kc) {
            half8 aF1 = *(const half8*)&arow[kc * 32 + q * 8];
            int kb = kc * 32 + q * 8;
            if (token >= kb && token < kb + 8)
                aF1[token - kb] = (_Float16)((float)aF1[token - kb] + 1.0f);
            #pragma unroll
            for (int nt = 0; nt < 12; ++nt) {
                half8 bF = *(const half8*)&srcpk[((b * 4 + kc) * 48 + wave * 12 + nt) * 512 + lane * 8];
                acc1[nt] = mfma16(aF1, bF, acc1[nt]);
            }
        }
        #pragma unroll
        for (int nt = 0; nt < 12; ++nt) {
            int n = wave * 192 + nt * 16 + col;
            #pragma unroll
            for (int r = 0; r < 4; ++r)
                sBuf[(q * 4 + r) * 776 + n] = f2h(acc1[nt][r]);
        }
    }
    __syncthreads();

    // phase 2: Y quarter nq; wave w -> 48 cols
    floatx4 acc2[3];
    #pragma unroll
    for (int nt = 0; nt < 3; ++nt) acc2[nt] = (floatx4){0.f, 0.f, 0.f, 0.f};
    for (int s = 0; s < 24; ++s) {
        half8 aF = *(const half8*)&sBuf[col * 776 + s * 32 + q * 8];
        #pragma unroll
        for (int nt = 0; nt < 3; ++nt) {
            int ntg = nq * 12 + wave * 3 + nt;
            half8 bF = *(const half8*)&gwp_l[(s * 48 + ntg) * 512 + lane * 8];
            acc2[nt] = mfma16(aF, bF, acc2[nt]);
        }
    }

    // epilogue: v = relu(Y*0.5 + gb); store yb; atomic LN partial sums
    float ps[4] = {0.f, 0.f, 0.f, 0.f}, pq[4] = {0.f, 0.f, 0.f, 0.f};
    #pragma unroll
    for (int nt = 0; nt < 3; ++nt) {
        int n = nq * 192 + wave * 48 + nt * 16 + col;
        float g = gb_l[n];
        #pragma unroll
        for (int r = 0; r < 4; ++r) {
            float v = fmaxf(acc2[nt][r] * 0.5f + g, 0.f);
            ps[r] += v; pq[r] += v * v;
            yb[(b * 128 + t0 + q * 4 + r) * 768 + n] = f2h(v);
        }
    }
    #pragma unroll
    for (int off = 1; off < 16; off <<= 1) {
        #pragma unroll
        for (int r = 0; r < 4; ++r) {
            ps[r] += __shfl_xor(ps[r], off);
            pq[r] += __shfl_xor(pq[r], off);
        }
    }
    if (col == 0) {
        #pragma unroll
        for (int r = 0; r < 4; ++r) {
            int row = b * 128 + t0 + q * 4 + r;
            atomicAdd(&gS[row], ps[r]);
            atomicAdd(&gQ[row], pq[r]);
        }
    }
}

// ---- GCN kernelB: LayerNorm apply; pack next-layer input OR write fp32 out -
// grid 1024 blocks (one token row) x 128 threads (96 active x 8 dims).
__global__ __launch_bounds__(128) void gcnB_kernel(
    const unsigned short* __restrict__ yb, float* __restrict__ gS,
    float* __restrict__ gQ, const float* __restrict__ lng_l,
    const float* __restrict__ lnb_l, unsigned short* __restrict__ spk,
    float* __restrict__ outf) {
    const int row = blockIdx.x, t = threadIdx.x;
    const float mu = gS[row] * (1.f / 768.f);
    const float va = gQ[row] * (1.f / 768.f) - mu * mu;  // biased var (jnp.var)
    const float rstd = rsqrtf(va + 1e-5f);
    if (t < 96) {
        union { uint4 u; unsigned short s[8]; } v;
        v.u = *(const uint4*)&yb[row * 768 + t * 8];
        if (outf) {
            #pragma unroll
            for (int e = 0; e < 8; ++e) {
                int d = t * 8 + e;
                outf[row * 768 + d] = (h2f(v.s[e]) - mu) * rstd * lng_l[d] + lnb_l[d];
            }
        } else {
            const int b = row >> 7, tok = row & 127;
            const int kc = tok >> 5, kl = tok & 31, kg = kl >> 3, e2 = kl & 7;
            #pragma unroll
            for (int e = 0; e < 8; ++e) {
                int d = t * 8 + e;
                float o = (h2f(v.s[e]) - mu) * rstd * lng_l[d] + lnb_l[d];
                spk[(((long)(b * 4 + kc) * 48 + (d >> 4)) * 512) +
                    (kg * 16 + (d & 15)) * 8 + e2] = f2h(o);
            }
        }
    }
    __syncthreads();
    if (t == 0) { gS[row] = 0.f; gQ[row] = 0.f; }  // self-zero for next layer
}

// ------------------------------- launch -------------------------------------
extern "C" void kernel_launch(void* const* d_in, const int* in_sizes, int n_in,
                              void* d_out, int out_size, void* d_ws, size_t ws_size,
                              hipStream_t stream) {
    const float* adj = (const float*)d_in[0];
    const float* x   = (const float*)d_in[1];
    const float* w1  = (const float*)d_in[2];
    const float* b1  = (const float*)d_in[3];
    const float* w2  = (const float*)d_in[4];
    const float* b2  = (const float*)d_in[5];
    const float* w3  = (const float*)d_in[6];
    const float* b3  = (const float*)d_in[7];
    const float* gw  = (const float*)d_in[8];
    const float* gb  = (const float*)d_in[9];
    const float* lng = (const float*)d_in[10];
    const float* lnb = (const float*)d_in[11];
    float* outp = (float*)d_out;  // 786432 out + 1024 mask

    char* ws = (char*)d_ws;
    unsigned short* w1t = (unsigned short*)(ws + 0);         // 1536x768 f16 [n][k]
    unsigned short* w2p = (unsigned short*)(ws + 2359296);   // 24x24x512 frag
    unsigned short* gwp = (unsigned short*)(ws + 2949120);   // 3x(24x48x512) frag
    unsigned short* xh  = (unsigned short*)(ws + 6488064);   // 1024x768 f16
    float*          hi  = (float*)        (ws + 8060928);    // 1024x768 fp32
    unsigned short* hjh = (unsigned short*)(ws + 11206656);  // 1024x768 f16
    unsigned short* ah  = (unsigned short*)(ws + 12779520);  // 8x128x128 f16
    unsigned short* xpk = (unsigned short*)(ws + 13041664);  // 8x4x48x512 frag
    unsigned short* yb  = (unsigned short*)(ws + 14614528);  // 1024x768 f16
    // aliases over dead regions:
    float* stats = (float*)(ws + 6488064);                   // gS|gQ (2x1024 f32), over xh
    float* gS = stats, *gQ = stats + 1024;
    unsigned short* spk0 = (unsigned short*)(ws + 0);        // over w1t
    unsigned short* spk1 = (unsigned short*)(ws + 11206656); // over hjh

    prep_kernel<<<dim3(24, 24, 15), dim3(32, 8), 0, stream>>>(
        x, w1, w2, gw, w1t, w2p, gwp, xh, xpk, outp + 786432);
    gemm128_kernel<<<dim3(12, 8), 256, 0, stream>>>(xh, w1t, hi, hjh);
    edge_kernel<<<512, 512, 0, stream>>>(hi, hjh, b1, w2p, b2, w3, b3, adj, ah, stats);

    const unsigned short* srcs[3] = { xpk, spk0, spk1 };
    unsigned short* dsts[3] = { spk0, spk1, nullptr };
    for (int li = 0; li < 3; ++li) {
        gcnA_kernel<<<dim3(4, 8, 8), 256, 0, stream>>>(
            ah, srcs[li], gwp + (long)li * 589824, gb + li * 768, yb, gS, gQ);
        gcnB_kernel<<<1024, 128, 0, stream>>>(
            yb, gS, gQ, lng + li * 768, lnb + li * 768, dsts[li],
            (li == 2) ? outp : nullptr);
    }
}